// Round 1
// baseline (3324.792 us; speedup 1.0000x reference)
//
#include <hip/hip_runtime.h>
#include <math.h>

// ---------------------------------------------------------------------------
// GCN: h1 = relu(Agg(x@W1)+b1); h2 = relu(Agg(h1@W2)+b2); out = mean_pool(h2)@fc_w + fc_b
// Agg(v) = sum_{e: col[e]=v} dinv[row]*dinv[col]*xw[row]  +  dinv[v]^2*xw[v]  (self loop)
// ---------------------------------------------------------------------------

__global__ void deg_kernel(const int* __restrict__ col, int* __restrict__ deg, int E) {
    int e = blockIdx.x * blockDim.x + threadIdx.x;
    if (e < E) atomicAdd(&deg[col[e]], 1);
}

// in-place: buf holds int degree counts, rewritten as float dinv
__global__ void dinv_kernel(float* __restrict__ buf, int N) {
    int v = blockIdx.x * blockDim.x + threadIdx.x;
    if (v < N) {
        int d = ((const int*)buf)[v] + 1;   // +1 for self loop
        buf[v] = 1.0f / sqrtf((float)d);
    }
}

// batch is sorted; binary-search graph boundaries. start[G] = N.
__global__ void bounds_kernel(const int* __restrict__ batch, int* __restrict__ start,
                              int N, int G) {
    int g = threadIdx.x;
    if (g > G) return;
    if (g == G) { start[G] = N; return; }
    int lo = 0, hi = N;
    while (lo < hi) { int mid = (lo + hi) >> 1; if (batch[mid] < g) lo = mid + 1; else hi = mid; }
    start[g] = lo;
}

// Y[N,128] = (RELU_IN ? relu(X) : X) @ W  (W is [128,128] row-major, staged in LDS)
// block: 256 threads, 128 rows; thread tile = 4 rows x 16 cols.
template<bool RELU_IN>
__global__ __launch_bounds__(256) void gemm128(const float* __restrict__ X,
                                               const float* __restrict__ W,
                                               float* __restrict__ Y, int N) {
    __shared__ float Wl[128 * 128];
    for (int i = threadIdx.x; i < 128 * 32; i += 256)
        ((float4*)Wl)[i] = ((const float4*)W)[i];
    __syncthreads();

    const int rg = threadIdx.x >> 3;   // 0..31
    const int cg = threadIdx.x & 7;    // 0..7
    const int r0 = blockIdx.x * 128 + rg * 4;
    const int c0 = cg * 16;

    float acc[4][16];
    #pragma unroll
    for (int i = 0; i < 4; ++i)
        #pragma unroll
        for (int j = 0; j < 16; ++j) acc[i][j] = 0.f;

    for (int k4 = 0; k4 < 32; ++k4) {
        float xb[4][4];
        #pragma unroll
        for (int i = 0; i < 4; ++i) {
            int r = r0 + i;
            float4 q = (r < N) ? *(const float4*)(X + (size_t)r * 128 + k4 * 4)
                               : make_float4(0.f, 0.f, 0.f, 0.f);
            if (RELU_IN) {
                q.x = fmaxf(q.x, 0.f); q.y = fmaxf(q.y, 0.f);
                q.z = fmaxf(q.z, 0.f); q.w = fmaxf(q.w, 0.f);
            }
            xb[i][0] = q.x; xb[i][1] = q.y; xb[i][2] = q.z; xb[i][3] = q.w;
        }
        #pragma unroll
        for (int kk = 0; kk < 4; ++kk) {
            const float* wr = &Wl[(k4 * 4 + kk) * 128 + c0];
            float4 w0 = *(const float4*)(wr + 0);
            float4 w1 = *(const float4*)(wr + 4);
            float4 w2 = *(const float4*)(wr + 8);
            float4 w3 = *(const float4*)(wr + 12);
            float wv[16] = { w0.x, w0.y, w0.z, w0.w, w1.x, w1.y, w1.z, w1.w,
                             w2.x, w2.y, w2.z, w2.w, w3.x, w3.y, w3.z, w3.w };
            #pragma unroll
            for (int i = 0; i < 4; ++i) {
                float xv = xb[i][kk];
                #pragma unroll
                for (int j = 0; j < 16; ++j) acc[i][j] = fmaf(xv, wv[j], acc[i][j]);
            }
        }
    }

    #pragma unroll
    for (int i = 0; i < 4; ++i) {
        int r = r0 + i;
        if (r < N) {
            #pragma unroll
            for (int j4 = 0; j4 < 4; ++j4) {
                *(float4*)(Y + (size_t)r * 128 + c0 + j4 * 4) =
                    make_float4(acc[i][j4 * 4 + 0], acc[i][j4 * 4 + 1],
                                acc[i][j4 * 4 + 2], acc[i][j4 * 4 + 3]);
            }
        }
    }
}

// h[v] = b + dinv[v]^2 * xw[v]   (bias + self-loop term; atomics add edges later)
__global__ void init_kernel(const float* __restrict__ xw, const float* __restrict__ dinv,
                            const float* __restrict__ b, float* __restrict__ h, int N) {
    int i = blockIdx.x * blockDim.x + threadIdx.x;   // float4 index
    if (i >= N * 32) return;
    int v = i >> 5, c4 = i & 31;
    float d = dinv[v];
    float d2 = d * d;
    float4 x = ((const float4*)xw)[i];
    float4 bb = ((const float4*)b)[c4];
    ((float4*)h)[i] = make_float4(bb.x + d2 * x.x, bb.y + d2 * x.y,
                                  bb.z + d2 * x.z, bb.w + d2 * x.w);
}

// one wave per edge; lane handles 2 of 128 feature floats
__global__ void agg_kernel(const float* __restrict__ xw, float* __restrict__ h,
                           const int* __restrict__ row, const int* __restrict__ col,
                           const float* __restrict__ dinv, int E) {
    int gtid = blockIdx.x * blockDim.x + threadIdx.x;
    int wave = gtid >> 6;
    int lane = threadIdx.x & 63;
    int nwaves = (gridDim.x * blockDim.x) >> 6;
    for (int e = wave; e < E; e += nwaves) {
        int r = row[e], c = col[e];
        float nrm = dinv[r] * dinv[c];
        float2 v = *(const float2*)(xw + (size_t)r * 128 + lane * 2);
        float* dst = h + (size_t)c * 128 + lane * 2;
        atomicAdd(dst + 0, nrm * v.x);
        atomicAdd(dst + 1, nrm * v.y);
    }
}

// out[g] = (sum_{v in graph g} sum_c relu(h[v][c]) * fc_w[c]) / max(cnt,1) + fc_b
__global__ __launch_bounds__(128) void pool_fc_kernel(const float* __restrict__ h,
                                                      const int* __restrict__ start,
                                                      const float* __restrict__ fc_w,
                                                      const float* __restrict__ fc_b,
                                                      float* __restrict__ out) {
    int g = blockIdx.x, c = threadIdx.x;
    int s = start[g], e = start[g + 1];
    float acc = 0.f;
    for (int v = s; v < e; ++v) acc += fmaxf(h[(size_t)v * 128 + c], 0.f);
    acc *= fc_w[c];
    __shared__ float red[128];
    red[c] = acc;
    __syncthreads();
    #pragma unroll
    for (int off = 64; off > 0; off >>= 1) {
        if (c < off) red[c] += red[c + off];
        __syncthreads();
    }
    if (c == 0) {
        float cnt = (float)(e - s);
        out[g] = red[0] / fmaxf(cnt, 1.f) + fc_b[0];
    }
}

extern "C" void kernel_launch(void* const* d_in, const int* in_sizes, int n_in,
                              void* d_out, int out_size, void* d_ws, size_t ws_size,
                              hipStream_t stream) {
    const float* x     = (const float*)d_in[0];
    const int*   ei    = (const int*)d_in[1];
    const int*   batch = (const int*)d_in[2];
    const float* W1    = (const float*)d_in[3];
    const float* b1    = (const float*)d_in[4];
    const float* W2    = (const float*)d_in[5];
    const float* b2    = (const float*)d_in[6];
    const float* fcw   = (const float*)d_in[7];
    const float* fcb   = (const float*)d_in[8];
    float* out = (float*)d_out;

    const int N = in_sizes[2];
    const int E = in_sizes[1] / 2;
    const int G = out_size;
    const int* row = ei;       // edge_index[0]
    const int* col = ei + E;   // edge_index[1]

    char* ws = (char*)d_ws;
    float* dinv = (float*)ws;                         // N floats (int deg first, in-place)
    size_t o = (((size_t)N * 4) + 511) & ~(size_t)511;
    int* start = (int*)(ws + o);                      // G+1 ints
    o += 512;
    float* bufA = (float*)(ws + o);                   // xw   [N,128]
    o += (size_t)N * 128 * 4;
    float* bufB = (float*)(ws + o);                   // h    [N,128]

    hipMemsetAsync(dinv, 0, (size_t)N * 4, stream);
    deg_kernel<<<(E + 255) / 256, 256, 0, stream>>>(col, (int*)dinv, E);
    dinv_kernel<<<(N + 255) / 256, 256, 0, stream>>>(dinv, N);
    bounds_kernel<<<1, 128, 0, stream>>>(batch, start, N, G);

    const int gemm_blocks = (N + 127) / 128;
    const int init_blocks = (N * 32 + 255) / 256;

    // layer 1
    gemm128<false><<<gemm_blocks, 256, 0, stream>>>(x, W1, bufA, N);
    init_kernel<<<init_blocks, 256, 0, stream>>>(bufA, dinv, b1, bufB, N);
    agg_kernel<<<2048, 256, 0, stream>>>(bufA, bufB, row, col, dinv, E);

    // layer 2 (relu fused into gemm input)
    gemm128<true><<<gemm_blocks, 256, 0, stream>>>(bufB, W2, bufA, N);
    init_kernel<<<init_blocks, 256, 0, stream>>>(bufA, dinv, b2, bufB, N);
    agg_kernel<<<2048, 256, 0, stream>>>(bufA, bufB, row, col, dinv, E);

    // pool + fc (relu fused into pool read)
    pool_fc_kernel<<<G, 128, 0, stream>>>(bufB, start, fcw, fcb, out);
}

// Round 2
// 1004.529 us; speedup vs baseline: 3.3098x; 3.3098x over previous
//
#include <hip/hip_runtime.h>
#include <math.h>

// ---------------------------------------------------------------------------
// GCN via destination-sorted CSR gather (no feature atomics):
//   h = relu( b + dinv[v]^2*xw[v] + dinv[v]*sum_e dinv[src]*xw[src] )
// CSR built once on device, reused for both layers.
// ---------------------------------------------------------------------------

__global__ void deg_kernel(const int* __restrict__ col, int* __restrict__ deg, int E) {
    int e = blockIdx.x * blockDim.x + threadIdx.x;
    if (e < E) atomicAdd(&deg[col[e]], 1);
}

__global__ void dinv_kernel(const int* __restrict__ deg, float* __restrict__ dinv, int N) {
    int v = blockIdx.x * blockDim.x + threadIdx.x;
    if (v < N) {
        int d = deg[v] + 1;   // +1 self loop
        dinv[v] = 1.0f / sqrtf((float)d);
    }
}

// ---- 3-kernel exclusive scan of deg[N] -> rowptr[N+1] (+ cursor copy) ----
__global__ void scan1(const int* __restrict__ deg, int* __restrict__ blocksum, int N) {
    __shared__ int sh[256];
    int base = blockIdx.x * 1024 + threadIdx.x * 4;
    int s = 0;
    #pragma unroll
    for (int k = 0; k < 4; ++k) { int i = base + k; if (i < N) s += deg[i]; }
    sh[threadIdx.x] = s; __syncthreads();
    for (int off = 128; off > 0; off >>= 1) {
        if (threadIdx.x < off) sh[threadIdx.x] += sh[threadIdx.x + off];
        __syncthreads();
    }
    if (threadIdx.x == 0) blocksum[blockIdx.x] = sh[0];
}

__global__ void scan2(int* __restrict__ blocksum, int nb) {
    __shared__ int sh[1024];
    int t = threadIdx.x;
    int orig = (t < nb) ? blocksum[t] : 0;
    sh[t] = orig; __syncthreads();
    for (int off = 1; off < 1024; off <<= 1) {
        int v = (t >= off) ? sh[t - off] : 0;
        __syncthreads();
        sh[t] += v;
        __syncthreads();
    }
    if (t < nb) blocksum[t] = sh[t] - orig;   // exclusive
}

__global__ void scan3(const int* __restrict__ deg, const int* __restrict__ blockoff,
                      int* __restrict__ rowptr, int* __restrict__ cursor, int N, int E) {
    __shared__ int sh[256];
    int t = threadIdx.x;
    int base = blockIdx.x * 1024 + t * 4;
    int v[4]; int s = 0;
    #pragma unroll
    for (int k = 0; k < 4; ++k) { int i = base + k; v[k] = (i < N) ? deg[i] : 0; s += v[k]; }
    int orig = s;
    sh[t] = s; __syncthreads();
    for (int off = 1; off < 256; off <<= 1) {
        int x = (t >= off) ? sh[t - off] : 0;
        __syncthreads();
        sh[t] += x;
        __syncthreads();
    }
    int run = blockoff[blockIdx.x] + sh[t] - orig;
    #pragma unroll
    for (int k = 0; k < 4; ++k) {
        int i = base + k;
        if (i < N) { rowptr[i] = run; cursor[i] = run; run += v[k]; }
    }
    if (blockIdx.x == 0 && t == 0) rowptr[N] = E;
}

__global__ void fill_kernel(const int* __restrict__ row, const int* __restrict__ col,
                            const float* __restrict__ dinv, int* __restrict__ cursor,
                            int* __restrict__ srcidx, float* __restrict__ wnorm, int E) {
    int e = blockIdx.x * blockDim.x + threadIdx.x;
    if (e < E) {
        int r = row[e], c = col[e];
        int p = atomicAdd(&cursor[c], 1);
        srcidx[p] = r;
        wnorm[p] = dinv[r] * dinv[c];
    }
}

// batch is sorted; binary-search graph boundaries. start[G] = N.
__global__ void bounds_kernel(const int* __restrict__ batch, int* __restrict__ start,
                              int N, int G) {
    int g = threadIdx.x;
    if (g > G) return;
    if (g == G) { start[G] = N; return; }
    int lo = 0, hi = N;
    while (lo < hi) { int mid = (lo + hi) >> 1; if (batch[mid] < g) lo = mid + 1; else hi = mid; }
    start[g] = lo;
}

// Y[N,128] = X @ W  (W is [128,128] row-major, staged in LDS)
__global__ __launch_bounds__(256) void gemm128(const float* __restrict__ X,
                                               const float* __restrict__ W,
                                               float* __restrict__ Y, int N) {
    __shared__ float Wl[128 * 128];
    for (int i = threadIdx.x; i < 128 * 32; i += 256)
        ((float4*)Wl)[i] = ((const float4*)W)[i];
    __syncthreads();

    const int rg = threadIdx.x >> 3;   // 0..31
    const int cg = threadIdx.x & 7;    // 0..7
    const int r0 = blockIdx.x * 128 + rg * 4;
    const int c0 = cg * 16;

    float acc[4][16];
    #pragma unroll
    for (int i = 0; i < 4; ++i)
        #pragma unroll
        for (int j = 0; j < 16; ++j) acc[i][j] = 0.f;

    for (int k4 = 0; k4 < 32; ++k4) {
        float xb[4][4];
        #pragma unroll
        for (int i = 0; i < 4; ++i) {
            int r = r0 + i;
            float4 q = (r < N) ? *(const float4*)(X + (size_t)r * 128 + k4 * 4)
                               : make_float4(0.f, 0.f, 0.f, 0.f);
            xb[i][0] = q.x; xb[i][1] = q.y; xb[i][2] = q.z; xb[i][3] = q.w;
        }
        #pragma unroll
        for (int kk = 0; kk < 4; ++kk) {
            const float* wr = &Wl[(k4 * 4 + kk) * 128 + c0];
            float4 w0 = *(const float4*)(wr + 0);
            float4 w1 = *(const float4*)(wr + 4);
            float4 w2 = *(const float4*)(wr + 8);
            float4 w3 = *(const float4*)(wr + 12);
            float wv[16] = { w0.x, w0.y, w0.z, w0.w, w1.x, w1.y, w1.z, w1.w,
                             w2.x, w2.y, w2.z, w2.w, w3.x, w3.y, w3.z, w3.w };
            #pragma unroll
            for (int i = 0; i < 4; ++i) {
                float xv = xb[i][kk];
                #pragma unroll
                for (int j = 0; j < 16; ++j) acc[i][j] = fmaf(xv, wv[j], acc[i][j]);
            }
        }
    }

    #pragma unroll
    for (int i = 0; i < 4; ++i) {
        int r = r0 + i;
        if (r < N) {
            #pragma unroll
            for (int j4 = 0; j4 < 4; ++j4) {
                *(float4*)(Y + (size_t)r * 128 + c0 + j4 * 4) =
                    make_float4(acc[i][j4 * 4 + 0], acc[i][j4 * 4 + 1],
                                acc[i][j4 * 4 + 2], acc[i][j4 * 4 + 3]);
            }
        }
    }
}

// one wave per destination node; lane owns 2 of 128 floats.
// out[v] = relu( b + dinv[v]^2*xw[v] + sum_e wnorm[e]*xw[srcidx[e]] )
__global__ __launch_bounds__(256) void gather_kernel(const float* __restrict__ xw,
                                                     const float* __restrict__ dinv,
                                                     const float* __restrict__ b,
                                                     const int* __restrict__ rowptr,
                                                     const int* __restrict__ srcidx,
                                                     const float* __restrict__ wnorm,
                                                     float* __restrict__ out, int N) {
    int wid = threadIdx.x >> 6, lane = threadIdx.x & 63;
    int v = blockIdx.x * 4 + wid;
    if (v >= N) return;
    int e0 = rowptr[v], e1 = rowptr[v + 1];
    int f = lane * 2;
    float d = dinv[v];
    float2 xs = *(const float2*)(xw + (size_t)v * 128 + f);
    float a0 = b[f]     + d * d * xs.x;
    float a1 = b[f + 1] + d * d * xs.y;
    int e = e0;
    for (; e + 1 < e1; e += 2) {
        int s0 = srcidx[e], s1 = srcidx[e + 1];
        float w0 = wnorm[e], w1 = wnorm[e + 1];
        float2 m0 = *(const float2*)(xw + (size_t)s0 * 128 + f);
        float2 m1 = *(const float2*)(xw + (size_t)s1 * 128 + f);
        a0 = fmaf(w0, m0.x, a0); a1 = fmaf(w0, m0.y, a1);
        a0 = fmaf(w1, m1.x, a0); a1 = fmaf(w1, m1.y, a1);
    }
    if (e < e1) {
        int s = srcidx[e]; float w = wnorm[e];
        float2 m = *(const float2*)(xw + (size_t)s * 128 + f);
        a0 = fmaf(w, m.x, a0); a1 = fmaf(w, m.y, a1);
    }
    a0 = fmaxf(a0, 0.f); a1 = fmaxf(a1, 0.f);
    *(float2*)(out + (size_t)v * 128 + f) = make_float2(a0, a1);
}

// out[g] = (sum_{v in g} sum_c h[v][c]*fc_w[c]) / max(cnt,1) + fc_b
__global__ __launch_bounds__(128) void pool_fc_kernel(const float* __restrict__ h,
                                                      const int* __restrict__ start,
                                                      const float* __restrict__ fc_w,
                                                      const float* __restrict__ fc_b,
                                                      float* __restrict__ out) {
    int g = blockIdx.x, c = threadIdx.x;
    int s = start[g], e = start[g + 1];
    float acc = 0.f;
    for (int v = s; v < e; ++v) acc += h[(size_t)v * 128 + c];
    acc *= fc_w[c];
    __shared__ float red[128];
    red[c] = acc;
    __syncthreads();
    #pragma unroll
    for (int off = 64; off > 0; off >>= 1) {
        if (c < off) red[c] += red[c + off];
        __syncthreads();
    }
    if (c == 0) {
        float cnt = (float)(e - s);
        out[g] = red[0] / fmaxf(cnt, 1.f) + fc_b[0];
    }
}

extern "C" void kernel_launch(void* const* d_in, const int* in_sizes, int n_in,
                              void* d_out, int out_size, void* d_ws, size_t ws_size,
                              hipStream_t stream) {
    const float* x     = (const float*)d_in[0];
    const int*   ei    = (const int*)d_in[1];
    const int*   batch = (const int*)d_in[2];
    const float* W1    = (const float*)d_in[3];
    const float* b1    = (const float*)d_in[4];
    const float* W2    = (const float*)d_in[5];
    const float* b2    = (const float*)d_in[6];
    const float* fcw   = (const float*)d_in[7];
    const float* fcb   = (const float*)d_in[8];
    float* out = (float*)d_out;

    const int N = in_sizes[2];
    const int E = in_sizes[1] / 2;
    const int G = out_size;
    const int* row = ei;       // edge_index[0]
    const int* col = ei + E;   // edge_index[1]

    auto align512 = [](size_t v) { return (v + 511) & ~(size_t)511; };
    char* ws = (char*)d_ws;
    size_t o = 0;
    int*   deg      = (int*)(ws + o);   o += align512((size_t)N * 4);
    float* dinv     = (float*)(ws + o); o += align512((size_t)N * 4);
    int*   rowptr   = (int*)(ws + o);   o += align512((size_t)(N + 1) * 4);
    int*   cursor   = (int*)(ws + o);   o += align512((size_t)N * 4);
    int*   blocksum = (int*)(ws + o);   o += align512(1024 * 4);
    int*   start    = (int*)(ws + o);   o += align512((size_t)(G + 1) * 4);
    int*   srcidx   = (int*)(ws + o);   o += align512((size_t)E * 4);
    float* wnorm    = (float*)(ws + o); o += align512((size_t)E * 4);
    float* bufA     = (float*)(ws + o); o += (size_t)N * 128 * 4;
    float* bufB     = (float*)(ws + o);

    const int nb = (N + 1023) / 1024;

    hipMemsetAsync(deg, 0, (size_t)N * 4, stream);
    deg_kernel<<<(E + 255) / 256, 256, 0, stream>>>(col, deg, E);
    dinv_kernel<<<(N + 255) / 256, 256, 0, stream>>>(deg, dinv, N);
    scan1<<<nb, 256, 0, stream>>>(deg, blocksum, N);
    scan2<<<1, 1024, 0, stream>>>(blocksum, nb);
    scan3<<<nb, 256, 0, stream>>>(deg, blocksum, rowptr, cursor, N, E);
    fill_kernel<<<(E + 255) / 256, 256, 0, stream>>>(row, col, dinv, cursor, srcidx, wnorm, E);
    bounds_kernel<<<1, 128, 0, stream>>>(batch, start, N, G);

    const int gemm_blocks = (N + 127) / 128;
    const int gather_blocks = (N + 3) / 4;

    // layer 1
    gemm128<<<gemm_blocks, 256, 0, stream>>>(x, W1, bufA, N);
    gather_kernel<<<gather_blocks, 256, 0, stream>>>(bufA, dinv, b1, rowptr, srcidx, wnorm, bufB, N);

    // layer 2
    gemm128<<<gemm_blocks, 256, 0, stream>>>(bufB, W2, bufA, N);
    gather_kernel<<<gather_blocks, 256, 0, stream>>>(bufA, dinv, b2, rowptr, srcidx, wnorm, bufB, N);

    // pool + fc
    pool_fc_kernel<<<G, 128, 0, stream>>>(bufB, start, fcw, fcb, out);
}

// Round 3
// 650.616 us; speedup vs baseline: 5.1102x; 1.5440x over previous
//
#include <hip/hip_runtime.h>
#include <math.h>

// ---------------------------------------------------------------------------
// GCN via destination-sorted CSR gather (no feature atomics):
//   h = relu( b + dinv[v]^2*xw[v] + sum_e wnorm[e]*xw[src[e]] )
// Layer 2's gather fuses the pooled-FC dot product: s[v] = relu(h2[v])@fc_w.
// ---------------------------------------------------------------------------

__global__ void deg_kernel(const int* __restrict__ col, int* __restrict__ deg, int E) {
    int e = blockIdx.x * blockDim.x + threadIdx.x;
    if (e < E) atomicAdd(&deg[col[e]], 1);
}

__global__ void dinv_kernel(const int* __restrict__ deg, float* __restrict__ dinv, int N) {
    int v = blockIdx.x * blockDim.x + threadIdx.x;
    if (v < N) {
        int d = deg[v] + 1;   // +1 self loop
        dinv[v] = 1.0f / sqrtf((float)d);
    }
}

// ---- 3-kernel exclusive scan of deg[N] -> rowptr[N+1] (+ cursor copy) ----
__global__ void scan1(const int* __restrict__ deg, int* __restrict__ blocksum, int N) {
    __shared__ int sh[256];
    int base = blockIdx.x * 1024 + threadIdx.x * 4;
    int s = 0;
    #pragma unroll
    for (int k = 0; k < 4; ++k) { int i = base + k; if (i < N) s += deg[i]; }
    sh[threadIdx.x] = s; __syncthreads();
    for (int off = 128; off > 0; off >>= 1) {
        if (threadIdx.x < off) sh[threadIdx.x] += sh[threadIdx.x + off];
        __syncthreads();
    }
    if (threadIdx.x == 0) blocksum[blockIdx.x] = sh[0];
}

__global__ void scan2(int* __restrict__ blocksum, int nb) {
    __shared__ int sh[1024];
    int t = threadIdx.x;
    int orig = (t < nb) ? blocksum[t] : 0;
    sh[t] = orig; __syncthreads();
    for (int off = 1; off < 1024; off <<= 1) {
        int v = (t >= off) ? sh[t - off] : 0;
        __syncthreads();
        sh[t] += v;
        __syncthreads();
    }
    if (t < nb) blocksum[t] = sh[t] - orig;   // exclusive
}

__global__ void scan3(const int* __restrict__ deg, const int* __restrict__ blockoff,
                      int* __restrict__ rowptr, int* __restrict__ cursor, int N, int E) {
    __shared__ int sh[256];
    int t = threadIdx.x;
    int base = blockIdx.x * 1024 + t * 4;
    int v[4]; int s = 0;
    #pragma unroll
    for (int k = 0; k < 4; ++k) { int i = base + k; v[k] = (i < N) ? deg[i] : 0; s += v[k]; }
    int orig = s;
    sh[t] = s; __syncthreads();
    for (int off = 1; off < 256; off <<= 1) {
        int x = (t >= off) ? sh[t - off] : 0;
        __syncthreads();
        sh[t] += x;
        __syncthreads();
    }
    int run = blockoff[blockIdx.x] + sh[t] - orig;
    #pragma unroll
    for (int k = 0; k < 4; ++k) {
        int i = base + k;
        if (i < N) { rowptr[i] = run; cursor[i] = run; run += v[k]; }
    }
    if (blockIdx.x == 0 && t == 0) rowptr[N] = E;
}

__global__ void fill_kernel(const int* __restrict__ row, const int* __restrict__ col,
                            const float* __restrict__ dinv, int* __restrict__ cursor,
                            int* __restrict__ srcidx, float* __restrict__ wnorm, int E) {
    int e = blockIdx.x * blockDim.x + threadIdx.x;
    if (e < E) {
        int r = row[e], c = col[e];
        int p = atomicAdd(&cursor[c], 1);
        srcidx[p] = r;
        wnorm[p] = dinv[r] * dinv[c];
    }
}

// batch is sorted; binary-search graph boundaries. start[G] = N.
__global__ void bounds_kernel(const int* __restrict__ batch, int* __restrict__ start,
                              int N, int G) {
    int g = threadIdx.x;
    if (g > G) return;
    if (g == G) { start[G] = N; return; }
    int lo = 0, hi = N;
    while (lo < hi) { int mid = (lo + hi) >> 1; if (batch[mid] < g) lo = mid + 1; else hi = mid; }
    start[g] = lo;
}

// Y[N,128] = X @ W  (W is [128,128] row-major, staged in LDS)
__global__ __launch_bounds__(256) void gemm128(const float* __restrict__ X,
                                               const float* __restrict__ W,
                                               float* __restrict__ Y, int N) {
    __shared__ float Wl[128 * 128];
    for (int i = threadIdx.x; i < 128 * 32; i += 256)
        ((float4*)Wl)[i] = ((const float4*)W)[i];
    __syncthreads();

    const int rg = threadIdx.x >> 3;   // 0..31
    const int cg = threadIdx.x & 7;    // 0..7
    const int r0 = blockIdx.x * 128 + rg * 4;
    const int c0 = cg * 16;

    float acc[4][16];
    #pragma unroll
    for (int i = 0; i < 4; ++i)
        #pragma unroll
        for (int j = 0; j < 16; ++j) acc[i][j] = 0.f;

    for (int k4 = 0; k4 < 32; ++k4) {
        float xb[4][4];
        #pragma unroll
        for (int i = 0; i < 4; ++i) {
            int r = r0 + i;
            float4 q = (r < N) ? *(const float4*)(X + (size_t)r * 128 + k4 * 4)
                               : make_float4(0.f, 0.f, 0.f, 0.f);
            xb[i][0] = q.x; xb[i][1] = q.y; xb[i][2] = q.z; xb[i][3] = q.w;
        }
        #pragma unroll
        for (int kk = 0; kk < 4; ++kk) {
            const float* wr = &Wl[(k4 * 4 + kk) * 128 + c0];
            float4 w0 = *(const float4*)(wr + 0);
            float4 w1 = *(const float4*)(wr + 4);
            float4 w2 = *(const float4*)(wr + 8);
            float4 w3 = *(const float4*)(wr + 12);
            float wv[16] = { w0.x, w0.y, w0.z, w0.w, w1.x, w1.y, w1.z, w1.w,
                             w2.x, w2.y, w2.z, w2.w, w3.x, w3.y, w3.z, w3.w };
            #pragma unroll
            for (int i = 0; i < 4; ++i) {
                float xv = xb[i][kk];
                #pragma unroll
                for (int j = 0; j < 16; ++j) acc[i][j] = fmaf(xv, wv[j], acc[i][j]);
            }
        }
    }

    #pragma unroll
    for (int i = 0; i < 4; ++i) {
        int r = r0 + i;
        if (r < N) {
            #pragma unroll
            for (int j4 = 0; j4 < 4; ++j4) {
                *(float4*)(Y + (size_t)r * 128 + c0 + j4 * 4) =
                    make_float4(acc[i][j4 * 4 + 0], acc[i][j4 * 4 + 1],
                                acc[i][j4 * 4 + 2], acc[i][j4 * 4 + 3]);
            }
        }
    }
}

// one wave per destination node; lane owns 2 of 128 floats.
// FC=false: out[v][:] = relu(b + dinv^2*xw[v] + sum wnorm*xw[src])   [N,128]
// FC=true : out[v]    = relu(same) @ fc_w                             [N]
template<bool FC>
__global__ __launch_bounds__(256) void gather_kernel(const float* __restrict__ xw,
                                                     const float* __restrict__ dinv,
                                                     const float* __restrict__ b,
                                                     const int* __restrict__ rowptr,
                                                     const int* __restrict__ srcidx,
                                                     const float* __restrict__ wnorm,
                                                     const float* __restrict__ fcw,
                                                     float* __restrict__ out, int N) {
    int wid = threadIdx.x >> 6, lane = threadIdx.x & 63;
    int v = blockIdx.x * 4 + wid;
    if (v >= N) return;
    int e0 = rowptr[v], e1 = rowptr[v + 1];
    int f = lane * 2;
    float d = dinv[v];
    float2 xs = *(const float2*)(xw + (size_t)v * 128 + f);
    float a0 = b[f]     + d * d * xs.x;
    float a1 = b[f + 1] + d * d * xs.y;
    int e = e0;
    for (; e + 1 < e1; e += 2) {
        int s0 = srcidx[e], s1 = srcidx[e + 1];
        float w0 = wnorm[e], w1 = wnorm[e + 1];
        float2 m0 = *(const float2*)(xw + (size_t)s0 * 128 + f);
        float2 m1 = *(const float2*)(xw + (size_t)s1 * 128 + f);
        a0 = fmaf(w0, m0.x, a0); a1 = fmaf(w0, m0.y, a1);
        a0 = fmaf(w1, m1.x, a0); a1 = fmaf(w1, m1.y, a1);
    }
    if (e < e1) {
        int s = srcidx[e]; float w = wnorm[e];
        float2 m = *(const float2*)(xw + (size_t)s * 128 + f);
        a0 = fmaf(w, m.x, a0); a1 = fmaf(w, m.y, a1);
    }
    a0 = fmaxf(a0, 0.f); a1 = fmaxf(a1, 0.f);
    if (!FC) {
        *(float2*)(out + (size_t)v * 128 + f) = make_float2(a0, a1);
    } else {
        float2 wv = *(const float2*)(fcw + f);
        float s = a0 * wv.x + a1 * wv.y;
        #pragma unroll
        for (int m = 32; m > 0; m >>= 1) s += __shfl_xor(s, m, 64);
        if (lane == 0) out[v] = s;
    }
}

// out[g] = (sum_{v in g} s[v]) / max(cnt,1) + fc_b    (one block per graph)
__global__ __launch_bounds__(256) void pool_kernel(const float* __restrict__ s,
                                                   const int* __restrict__ start,
                                                   const float* __restrict__ fc_b,
                                                   float* __restrict__ out) {
    int g = blockIdx.x;
    int s0 = start[g], s1 = start[g + 1];
    float acc = 0.f;
    for (int v = s0 + threadIdx.x; v < s1; v += 256) acc += s[v];
    __shared__ float red[256];
    red[threadIdx.x] = acc;
    __syncthreads();
    #pragma unroll
    for (int off = 128; off > 0; off >>= 1) {
        if (threadIdx.x < off) red[threadIdx.x] += red[threadIdx.x + off];
        __syncthreads();
    }
    if (threadIdx.x == 0) {
        float cnt = (float)(s1 - s0);
        out[g] = red[0] / fmaxf(cnt, 1.f) + fc_b[0];
    }
}

extern "C" void kernel_launch(void* const* d_in, const int* in_sizes, int n_in,
                              void* d_out, int out_size, void* d_ws, size_t ws_size,
                              hipStream_t stream) {
    const float* x     = (const float*)d_in[0];
    const int*   ei    = (const int*)d_in[1];
    const int*   batch = (const int*)d_in[2];
    const float* W1    = (const float*)d_in[3];
    const float* b1    = (const float*)d_in[4];
    const float* W2    = (const float*)d_in[5];
    const float* b2    = (const float*)d_in[6];
    const float* fcw   = (const float*)d_in[7];
    const float* fcb   = (const float*)d_in[8];
    float* out = (float*)d_out;

    const int N = in_sizes[2];
    const int E = in_sizes[1] / 2;
    const int G = out_size;
    const int* row = ei;       // edge_index[0]
    const int* col = ei + E;   // edge_index[1]

    auto align512 = [](size_t v) { return (v + 511) & ~(size_t)511; };
    char* ws = (char*)d_ws;
    size_t o = 0;
    int*   deg      = (int*)(ws + o);   o += align512((size_t)N * 4);
    float* dinv     = (float*)(ws + o); o += align512((size_t)N * 4);
    int*   rowptr   = (int*)(ws + o);   o += align512((size_t)(N + 1) * 4);
    int*   cursor   = (int*)(ws + o);   o += align512((size_t)N * 4);
    int*   blocksum = (int*)(ws + o);   o += align512(1024 * 4);
    int*   start    = (int*)(ws + o);   o += align512((size_t)(G + 1) * 4);
    float* nodesc   = (float*)(ws + o); o += align512((size_t)N * 4);
    int*   srcidx   = (int*)(ws + o);   o += align512((size_t)E * 4);
    float* wnorm    = (float*)(ws + o); o += align512((size_t)E * 4);
    float* bufA     = (float*)(ws + o); o += (size_t)N * 128 * 4;
    float* bufB     = (float*)(ws + o);

    const int nb = (N + 1023) / 1024;

    hipMemsetAsync(deg, 0, (size_t)N * 4, stream);
    deg_kernel<<<(E + 255) / 256, 256, 0, stream>>>(col, deg, E);
    dinv_kernel<<<(N + 255) / 256, 256, 0, stream>>>(deg, dinv, N);
    scan1<<<nb, 256, 0, stream>>>(deg, blocksum, N);
    scan2<<<1, 1024, 0, stream>>>(blocksum, nb);
    scan3<<<nb, 256, 0, stream>>>(deg, blocksum, rowptr, cursor, N, E);
    fill_kernel<<<(E + 255) / 256, 256, 0, stream>>>(row, col, dinv, cursor, srcidx, wnorm, E);
    bounds_kernel<<<1, 128, 0, stream>>>(batch, start, N, G);

    const int gemm_blocks = (N + 127) / 128;
    const int gather_blocks = (N + 3) / 4;

    // layer 1
    gemm128<<<gemm_blocks, 256, 0, stream>>>(x, W1, bufA, N);
    gather_kernel<false><<<gather_blocks, 256, 0, stream>>>(bufA, dinv, b1, rowptr, srcidx,
                                                            wnorm, nullptr, bufB, N);

    // layer 2: gather fuses relu + fc dot -> per-node scalar
    gemm128<<<gemm_blocks, 256, 0, stream>>>(bufB, W2, bufA, N);
    gather_kernel<true><<<gather_blocks, 256, 0, stream>>>(bufA, dinv, b2, rowptr, srcidx,
                                                           wnorm, fcw, nodesc, N);

    // segmented mean over per-node scalars
    pool_kernel<<<G, 256, 0, stream>>>(nodesc, start, fcb, out);
}

// Round 4
// 498.843 us; speedup vs baseline: 6.6650x; 1.3042x over previous
//
#include <hip/hip_runtime.h>
#include <hip/hip_bf16.h>
#include <math.h>

// ---------------------------------------------------------------------------
// GCN via destination-sorted CSR gather. Node features between stages are
// stored as bf16 (gather traffic halved); all accumulation is fp32.
//   h = relu( b + dinv[v]^2*xw[v] + sum_e wnorm[e]*xw[src[e]] )
// Layer 2's gather fuses the pooled-FC dot product.
// ---------------------------------------------------------------------------

__device__ inline unsigned pack_bf16(float a, float b) {
    __hip_bfloat16 ha = __float2bfloat16(a);   // RNE
    __hip_bfloat16 hb = __float2bfloat16(b);
    unsigned short ua = *(unsigned short*)&ha;
    unsigned short ub = *(unsigned short*)&hb;
    return (unsigned)ua | ((unsigned)ub << 16);
}

__device__ inline float2 unpack_bf16(unsigned u) {
    return make_float2(__uint_as_float(u << 16), __uint_as_float(u & 0xffff0000u));
}

__global__ void deg_kernel(const int* __restrict__ col, int* __restrict__ deg, int E) {
    int e = blockIdx.x * blockDim.x + threadIdx.x;
    if (e < E) atomicAdd(&deg[col[e]], 1);
}

__global__ void dinv_kernel(const int* __restrict__ deg, float* __restrict__ dinv, int N) {
    int v = blockIdx.x * blockDim.x + threadIdx.x;
    if (v < N) {
        int d = deg[v] + 1;   // +1 self loop
        dinv[v] = 1.0f / sqrtf((float)d);
    }
}

// ---- 3-kernel exclusive scan of deg[N] -> rowptr[N+1] (+ cursor copy) ----
__global__ void scan1(const int* __restrict__ deg, int* __restrict__ blocksum, int N) {
    __shared__ int sh[256];
    int base = blockIdx.x * 1024 + threadIdx.x * 4;
    int s = 0;
    #pragma unroll
    for (int k = 0; k < 4; ++k) { int i = base + k; if (i < N) s += deg[i]; }
    sh[threadIdx.x] = s; __syncthreads();
    for (int off = 128; off > 0; off >>= 1) {
        if (threadIdx.x < off) sh[threadIdx.x] += sh[threadIdx.x + off];
        __syncthreads();
    }
    if (threadIdx.x == 0) blocksum[blockIdx.x] = sh[0];
}

__global__ void scan2(int* __restrict__ blocksum, int nb) {
    __shared__ int sh[1024];
    int t = threadIdx.x;
    int orig = (t < nb) ? blocksum[t] : 0;
    sh[t] = orig; __syncthreads();
    for (int off = 1; off < 1024; off <<= 1) {
        int v = (t >= off) ? sh[t - off] : 0;
        __syncthreads();
        sh[t] += v;
        __syncthreads();
    }
    if (t < nb) blocksum[t] = sh[t] - orig;   // exclusive
}

__global__ void scan3(const int* __restrict__ deg, const int* __restrict__ blockoff,
                      int* __restrict__ rowptr, int* __restrict__ cursor, int N, int E) {
    __shared__ int sh[256];
    int t = threadIdx.x;
    int base = blockIdx.x * 1024 + t * 4;
    int v[4]; int s = 0;
    #pragma unroll
    for (int k = 0; k < 4; ++k) { int i = base + k; v[k] = (i < N) ? deg[i] : 0; s += v[k]; }
    int orig = s;
    sh[t] = s; __syncthreads();
    for (int off = 1; off < 256; off <<= 1) {
        int x = (t >= off) ? sh[t - off] : 0;
        __syncthreads();
        sh[t] += x;
        __syncthreads();
    }
    int run = blockoff[blockIdx.x] + sh[t] - orig;
    #pragma unroll
    for (int k = 0; k < 4; ++k) {
        int i = base + k;
        if (i < N) { rowptr[i] = run; cursor[i] = run; run += v[k]; }
    }
    if (blockIdx.x == 0 && t == 0) rowptr[N] = E;
}

__global__ void fill_kernel(const int* __restrict__ row, const int* __restrict__ col,
                            const float* __restrict__ dinv, int* __restrict__ cursor,
                            int2* __restrict__ emeta, int E) {
    int e = blockIdx.x * blockDim.x + threadIdx.x;
    if (e < E) {
        int r = row[e], c = col[e];
        int p = atomicAdd(&cursor[c], 1);
        emeta[p] = make_int2(r, __float_as_int(dinv[r] * dinv[c]));
    }
}

__global__ void bounds_kernel(const int* __restrict__ batch, int* __restrict__ start,
                              int N, int G) {
    int g = threadIdx.x;
    if (g > G) return;
    if (g == G) { start[G] = N; return; }
    int lo = 0, hi = N;
    while (lo < hi) { int mid = (lo + hi) >> 1; if (batch[mid] < g) lo = mid + 1; else hi = mid; }
    start[g] = lo;
}

// Yb[N,128](bf16) = X[N,128](f32) @ W[128,128](f32, staged in LDS)
// 256 threads; thread tile = 8 rows x 16 cols (acc in 128 VGPRs).
__global__ __launch_bounds__(256, 2) void gemm128(const float* __restrict__ X,
                                                  const float* __restrict__ W,
                                                  unsigned* __restrict__ Yb, int N) {
    __shared__ float Wl[128 * 128];
    for (int i = threadIdx.x; i < 128 * 32; i += 256)
        ((float4*)Wl)[i] = ((const float4*)W)[i];
    __syncthreads();

    const int rg = threadIdx.x >> 3;   // 0..31
    const int cg = threadIdx.x & 7;    // 0..7
    const int r0 = blockIdx.x * 256 + rg * 8;
    const int c0 = cg * 16;

    float acc[8][16];
    #pragma unroll
    for (int i = 0; i < 8; ++i)
        #pragma unroll
        for (int j = 0; j < 16; ++j) acc[i][j] = 0.f;

    for (int k4 = 0; k4 < 32; ++k4) {
        float xb[8][4];
        #pragma unroll
        for (int i = 0; i < 8; ++i) {
            int r = r0 + i;
            float4 q = (r < N) ? *(const float4*)(X + (size_t)r * 128 + k4 * 4)
                               : make_float4(0.f, 0.f, 0.f, 0.f);
            xb[i][0] = q.x; xb[i][1] = q.y; xb[i][2] = q.z; xb[i][3] = q.w;
        }
        #pragma unroll
        for (int kk = 0; kk < 4; ++kk) {
            const float* wr = &Wl[(k4 * 4 + kk) * 128 + c0];
            float4 w0 = *(const float4*)(wr + 0);
            float4 w1 = *(const float4*)(wr + 4);
            float4 w2 = *(const float4*)(wr + 8);
            float4 w3 = *(const float4*)(wr + 12);
            float wv[16] = { w0.x, w0.y, w0.z, w0.w, w1.x, w1.y, w1.z, w1.w,
                             w2.x, w2.y, w2.z, w2.w, w3.x, w3.y, w3.z, w3.w };
            #pragma unroll
            for (int i = 0; i < 8; ++i) {
                float xv = xb[i][kk];
                #pragma unroll
                for (int j = 0; j < 16; ++j) acc[i][j] = fmaf(xv, wv[j], acc[i][j]);
            }
        }
    }

    #pragma unroll
    for (int i = 0; i < 8; ++i) {
        int r = r0 + i;
        if (r < N) {
            uint4 p0, p1;
            p0.x = pack_bf16(acc[i][0],  acc[i][1]);
            p0.y = pack_bf16(acc[i][2],  acc[i][3]);
            p0.z = pack_bf16(acc[i][4],  acc[i][5]);
            p0.w = pack_bf16(acc[i][6],  acc[i][7]);
            p1.x = pack_bf16(acc[i][8],  acc[i][9]);
            p1.y = pack_bf16(acc[i][10], acc[i][11]);
            p1.z = pack_bf16(acc[i][12], acc[i][13]);
            p1.w = pack_bf16(acc[i][14], acc[i][15]);
            *(uint4*)(Yb + (size_t)r * 64 + c0 / 2)     = p0;
            *(uint4*)(Yb + (size_t)r * 64 + c0 / 2 + 4) = p1;
        }
    }
}

// one wave per destination node; lane owns cols {2l, 2l+1} (one bf16x2 dword).
// FC=false: out[v][:] = relu(b + dinv^2*xw[v] + sum wnorm*xw[src])  fp32 [N,128]
// FC=true : out[v]    = relu(same) @ fc_w                           fp32 [N]
template<bool FC>
__global__ __launch_bounds__(256) void gather_kernel(const unsigned* __restrict__ xwb,
                                                     const float* __restrict__ dinv,
                                                     const float* __restrict__ b,
                                                     const int* __restrict__ rowptr,
                                                     const int2* __restrict__ emeta,
                                                     const float* __restrict__ fcw,
                                                     float* __restrict__ out, int N) {
    int wid = threadIdx.x >> 6, lane = threadIdx.x & 63;
    int v = blockIdx.x * 4 + wid;
    if (v >= N) return;
    int e0 = rowptr[v], e1 = rowptr[v + 1];
    float d = dinv[v];
    float2 xs = unpack_bf16(xwb[v * 64 + lane]);
    float2 bb = *(const float2*)(b + 2 * lane);
    float a0 = bb.x + d * d * xs.x;
    float a1 = bb.y + d * d * xs.y;

    int e = e0;
    for (; e + 4 <= e1; e += 4) {
        int2 m0 = emeta[e], m1 = emeta[e + 1], m2 = emeta[e + 2], m3 = emeta[e + 3];
        unsigned u0 = xwb[m0.x * 64 + lane];
        unsigned u1 = xwb[m1.x * 64 + lane];
        unsigned u2 = xwb[m2.x * 64 + lane];
        unsigned u3 = xwb[m3.x * 64 + lane];
        float w0 = __int_as_float(m0.y), w1 = __int_as_float(m1.y);
        float w2 = __int_as_float(m2.y), w3 = __int_as_float(m3.y);
        float2 f0 = unpack_bf16(u0), f1 = unpack_bf16(u1);
        float2 f2 = unpack_bf16(u2), f3 = unpack_bf16(u3);
        a0 = fmaf(w0, f0.x, a0); a1 = fmaf(w0, f0.y, a1);
        a0 = fmaf(w1, f1.x, a0); a1 = fmaf(w1, f1.y, a1);
        a0 = fmaf(w2, f2.x, a0); a1 = fmaf(w2, f2.y, a1);
        a0 = fmaf(w3, f3.x, a0); a1 = fmaf(w3, f3.y, a1);
    }
    for (; e < e1; ++e) {
        int2 m = emeta[e];
        float2 f = unpack_bf16(xwb[m.x * 64 + lane]);
        float w = __int_as_float(m.y);
        a0 = fmaf(w, f.x, a0); a1 = fmaf(w, f.y, a1);
    }

    a0 = fmaxf(a0, 0.f); a1 = fmaxf(a1, 0.f);
    if (!FC) {
        *(float2*)(out + (size_t)v * 128 + 2 * lane) = make_float2(a0, a1);
    } else {
        float2 wv = *(const float2*)(fcw + 2 * lane);
        float s = a0 * wv.x + a1 * wv.y;
        #pragma unroll
        for (int m = 32; m > 0; m >>= 1) s += __shfl_xor(s, m, 64);
        if (lane == 0) out[v] = s;
    }
}

// out[g] = (sum_{v in g} s[v]) / max(cnt,1) + fc_b    (one block per graph)
__global__ __launch_bounds__(256) void pool_kernel(const float* __restrict__ s,
                                                   const int* __restrict__ start,
                                                   const float* __restrict__ fc_b,
                                                   float* __restrict__ out) {
    int g = blockIdx.x;
    int s0 = start[g], s1 = start[g + 1];
    float acc = 0.f;
    for (int v = s0 + threadIdx.x; v < s1; v += 256) acc += s[v];
    __shared__ float red[256];
    red[threadIdx.x] = acc;
    __syncthreads();
    #pragma unroll
    for (int off = 128; off > 0; off >>= 1) {
        if (threadIdx.x < off) red[threadIdx.x] += red[threadIdx.x + off];
        __syncthreads();
    }
    if (threadIdx.x == 0) {
        float cnt = (float)(s1 - s0);
        out[g] = red[0] / fmaxf(cnt, 1.f) + fc_b[0];
    }
}

extern "C" void kernel_launch(void* const* d_in, const int* in_sizes, int n_in,
                              void* d_out, int out_size, void* d_ws, size_t ws_size,
                              hipStream_t stream) {
    const float* x     = (const float*)d_in[0];
    const int*   ei    = (const int*)d_in[1];
    const int*   batch = (const int*)d_in[2];
    const float* W1    = (const float*)d_in[3];
    const float* b1    = (const float*)d_in[4];
    const float* W2    = (const float*)d_in[5];
    const float* b2    = (const float*)d_in[6];
    const float* fcw   = (const float*)d_in[7];
    const float* fcb   = (const float*)d_in[8];
    float* out = (float*)d_out;

    const int N = in_sizes[2];
    const int E = in_sizes[1] / 2;
    const int G = out_size;
    const int* row = ei;       // edge_index[0]
    const int* col = ei + E;   // edge_index[1]

    auto align512 = [](size_t v) { return (v + 511) & ~(size_t)511; };
    char* ws = (char*)d_ws;
    size_t o = 0;
    int*      deg      = (int*)(ws + o);      o += align512((size_t)N * 4);
    float*    dinv     = (float*)(ws + o);    o += align512((size_t)N * 4);
    int*      rowptr   = (int*)(ws + o);      o += align512((size_t)(N + 1) * 4);
    int*      cursor   = (int*)(ws + o);      o += align512((size_t)N * 4);
    int*      blocksum = (int*)(ws + o);      o += align512(1024 * 4);
    int*      start    = (int*)(ws + o);      o += align512((size_t)(G + 1) * 4);
    float*    nodesc   = (float*)(ws + o);    o += align512((size_t)N * 4);
    int2*     emeta    = (int2*)(ws + o);     o += align512((size_t)E * 8);
    unsigned* bufBF    = (unsigned*)(ws + o); o += align512((size_t)N * 64 * 4);
    float*    bufH     = (float*)(ws + o);

    const int nb = (N + 1023) / 1024;

    hipMemsetAsync(deg, 0, (size_t)N * 4, stream);
    deg_kernel<<<(E + 255) / 256, 256, 0, stream>>>(col, deg, E);
    dinv_kernel<<<(N + 255) / 256, 256, 0, stream>>>(deg, dinv, N);
    scan1<<<nb, 256, 0, stream>>>(deg, blocksum, N);
    scan2<<<1, 1024, 0, stream>>>(blocksum, nb);
    scan3<<<nb, 256, 0, stream>>>(deg, blocksum, rowptr, cursor, N, E);
    fill_kernel<<<(E + 255) / 256, 256, 0, stream>>>(row, col, dinv, cursor, emeta, E);
    bounds_kernel<<<1, 128, 0, stream>>>(batch, start, N, G);

    const int gemm_blocks = (N + 255) / 256;
    const int gather_blocks = (N + 3) / 4;

    // layer 1
    gemm128<<<gemm_blocks, 256, 0, stream>>>(x, W1, bufBF, N);
    gather_kernel<false><<<gather_blocks, 256, 0, stream>>>(bufBF, dinv, b1, rowptr, emeta,
                                                            nullptr, bufH, N);

    // layer 2: gather fuses relu + fc dot -> per-node scalar
    gemm128<<<gemm_blocks, 256, 0, stream>>>(bufH, W2, bufBF, N);
    gather_kernel<true><<<gather_blocks, 256, 0, stream>>>(bufBF, dinv, b2, rowptr, emeta,
                                                           fcw, nodesc, N);

    // segmented mean over per-node scalars
    pool_kernel<<<G, 256, 0, stream>>>(nodesc, start, fcb, out);
}

// Round 5
// 354.994 us; speedup vs baseline: 9.3658x; 1.4052x over previous
//
#include <hip/hip_runtime.h>
#include <hip/hip_bf16.h>
#include <math.h>

// ---------------------------------------------------------------------------
// GCN via destination-sorted CSR gather + bf16 MFMA feature transform.
//   h = relu( b + dinv[v]^2*xw[v] + sum_e wnorm[e]*xw[src[e]] )
// All inter-stage node features are packed bf16x2 dwords [N,64].
// ---------------------------------------------------------------------------

typedef __attribute__((ext_vector_type(8))) short bf16x8;
typedef __attribute__((ext_vector_type(4))) float f32x4;

union U4 { uint4 u; bf16x8 h; };

__device__ inline unsigned pack_bf16(float a, float b) {
    __hip_bfloat16 ha = __float2bfloat16(a);   // RNE
    __hip_bfloat16 hb = __float2bfloat16(b);
    unsigned short ua = *(unsigned short*)&ha;
    unsigned short ub = *(unsigned short*)&hb;
    return (unsigned)ua | ((unsigned)ub << 16);
}

__device__ inline float2 unpack_bf16(unsigned u) {
    return make_float2(__uint_as_float(u << 16), __uint_as_float(u & 0xffff0000u));
}

__global__ void deg_kernel(const int* __restrict__ col, int* __restrict__ deg, int E) {
    int e = blockIdx.x * blockDim.x + threadIdx.x;
    if (e < E) atomicAdd(&deg[col[e]], 1);
}

__global__ void dinv_kernel(const int* __restrict__ deg, float* __restrict__ dinv, int N) {
    int v = blockIdx.x * blockDim.x + threadIdx.x;
    if (v < N) {
        int d = deg[v] + 1;   // +1 self loop
        dinv[v] = 1.0f / sqrtf((float)d);
    }
}

// ---- 3-kernel exclusive scan of deg[N] -> rowptr[N+1] (+ cursor copy) ----
__global__ void scan1(const int* __restrict__ deg, int* __restrict__ blocksum, int N) {
    __shared__ int sh[256];
    int base = blockIdx.x * 1024 + threadIdx.x * 4;
    int s = 0;
    #pragma unroll
    for (int k = 0; k < 4; ++k) { int i = base + k; if (i < N) s += deg[i]; }
    sh[threadIdx.x] = s; __syncthreads();
    for (int off = 128; off > 0; off >>= 1) {
        if (threadIdx.x < off) sh[threadIdx.x] += sh[threadIdx.x + off];
        __syncthreads();
    }
    if (threadIdx.x == 0) blocksum[blockIdx.x] = sh[0];
}

__global__ void scan2(int* __restrict__ blocksum, int nb) {
    __shared__ int sh[1024];
    int t = threadIdx.x;
    int orig = (t < nb) ? blocksum[t] : 0;
    sh[t] = orig; __syncthreads();
    for (int off = 1; off < 1024; off <<= 1) {
        int v = (t >= off) ? sh[t - off] : 0;
        __syncthreads();
        sh[t] += v;
        __syncthreads();
    }
    if (t < nb) blocksum[t] = sh[t] - orig;   // exclusive
}

__global__ void scan3(const int* __restrict__ deg, const int* __restrict__ blockoff,
                      int* __restrict__ rowptr, int* __restrict__ cursor, int N, int E) {
    __shared__ int sh[256];
    int t = threadIdx.x;
    int base = blockIdx.x * 1024 + t * 4;
    int v[4]; int s = 0;
    #pragma unroll
    for (int k = 0; k < 4; ++k) { int i = base + k; v[k] = (i < N) ? deg[i] : 0; s += v[k]; }
    int orig = s;
    sh[t] = s; __syncthreads();
    for (int off = 1; off < 256; off <<= 1) {
        int x = (t >= off) ? sh[t - off] : 0;
        __syncthreads();
        sh[t] += x;
        __syncthreads();
    }
    int run = blockoff[blockIdx.x] + sh[t] - orig;
    #pragma unroll
    for (int k = 0; k < 4; ++k) {
        int i = base + k;
        if (i < N) { rowptr[i] = run; cursor[i] = run; run += v[k]; }
    }
    if (blockIdx.x == 0 && t == 0) rowptr[N] = E;
}

__global__ void fill_kernel(const int* __restrict__ row, const int* __restrict__ col,
                            const float* __restrict__ dinv, int* __restrict__ cursor,
                            int2* __restrict__ emeta, int E) {
    int e = blockIdx.x * blockDim.x + threadIdx.x;
    if (e < E) {
        int r = row[e], c = col[e];
        int p = atomicAdd(&cursor[c], 1);
        emeta[p] = make_int2(r, __float_as_int(dinv[r] * dinv[c]));
    }
}

__global__ void bounds_kernel(const int* __restrict__ batch, int* __restrict__ start,
                              int N, int G) {
    int g = threadIdx.x;
    if (g > G) return;
    if (g == G) { start[G] = N; return; }
    int lo = 0, hi = N;
    while (lo < hi) { int mid = (lo + hi) >> 1; if (batch[mid] < g) lo = mid + 1; else hi = mid; }
    start[g] = lo;
}

// W[128,128] f32 -> fragment-ordered bf16: Wf[f*256 + l*4 + i] covers
// n = (f>>2)*16 + (l&15), k = (f&3)*32 + 8*(l>>4) + 2i (+0,+1).
// grid = 32 blocks x 256 threads, one dword per thread.
__global__ void wprep_kernel(const float* __restrict__ W, unsigned* __restrict__ Wf) {
    int f = blockIdx.x, t = threadIdx.x;
    int l = t >> 2, i = t & 3;
    int n = (f >> 2) * 16 + (l & 15);
    int k = (f & 3) * 32 + 8 * (l >> 4) + 2 * i;
    Wf[f * 256 + t] = pack_bf16(W[k * 128 + n], W[(k + 1) * 128 + n]);
}

// Yb[N,64](bf16x2) = X @ W via mfma_f32_16x16x32_bf16.
// Block = 256 thr = 4 waves; wave handles 4 row-tiles of 16 (256 rows/block).
// IN_F32: X is f32 [N,128]; else packed bf16 [N,64] dwords.
template<bool IN_F32>
__global__ __launch_bounds__(256) void gemm_mfma(const void* __restrict__ Xv,
                                                 const unsigned* __restrict__ Wf,
                                                 unsigned* __restrict__ Yb, int N) {
    __shared__ unsigned wl[8192];   // 32 fragments x 64 lanes x 4 dwords
    for (int i = threadIdx.x; i < 2048; i += 256)
        ((uint4*)wl)[i] = ((const uint4*)Wf)[i];
    __syncthreads();

    const int w  = threadIdx.x >> 6;
    const int l  = threadIdx.x & 63;
    const int lm = l & 15;           // A row-in-tile / D col
    const int lg = l >> 4;           // k-group
    const int base_row = blockIdx.x * 256 + w * 64;

    for (int t = 0; t < 4; ++t) {
        const int row = base_row + t * 16 + lm;
        const bool ok = row < N;
        U4 a[4];
        if (IN_F32) {
            const float* X = (const float*)Xv;
            #pragma unroll
            for (int kk = 0; kk < 4; ++kk) {
                if (ok) {
                    const float* p = X + (size_t)row * 128 + kk * 32 + lg * 8;
                    float4 q0 = *(const float4*)(p);
                    float4 q1 = *(const float4*)(p + 4);
                    a[kk].u = make_uint4(pack_bf16(q0.x, q0.y), pack_bf16(q0.z, q0.w),
                                         pack_bf16(q1.x, q1.y), pack_bf16(q1.z, q1.w));
                } else a[kk].u = make_uint4(0, 0, 0, 0);
            }
        } else {
            const uint4* X = (const uint4*)Xv;   // 16 uint4 per row
            #pragma unroll
            for (int kk = 0; kk < 4; ++kk)
                a[kk].u = ok ? X[(size_t)row * 16 + kk * 4 + lg] : make_uint4(0, 0, 0, 0);
        }

        f32x4 acc[8];
        #pragma unroll
        for (int nt = 0; nt < 8; ++nt) acc[nt] = (f32x4){0.f, 0.f, 0.f, 0.f};

        #pragma unroll
        for (int kk = 0; kk < 4; ++kk) {
            #pragma unroll
            for (int nt = 0; nt < 8; ++nt) {
                bf16x8 b = *(const bf16x8*)&wl[(nt * 4 + kk) * 256 + l * 4];
                acc[nt] = __builtin_amdgcn_mfma_f32_16x16x32_bf16(a[kk].h, b, acc[nt], 0, 0, 0);
            }
        }

        // D: lane holds rows lg*4+r, col lm (per nt). Pack col pairs via lane^1.
        #pragma unroll
        for (int r = 0; r < 4; ++r) {
            const int orow = base_row + t * 16 + lg * 4 + r;
            #pragma unroll
            for (int nt = 0; nt < 8; ++nt) {
                float v = acc[nt][r];
                float pv = __shfl_xor(v, 1, 64);
                if (!(lm & 1) && orow < N)
                    Yb[(size_t)orow * 64 + nt * 8 + (lm >> 1)] = pack_bf16(v, pv);
            }
        }
    }
}

// one wave per destination node; lane owns cols {2l, 2l+1} (one bf16x2 dword).
// FC=false: outb[v][:] = relu(...) packed bf16 [N,64]
// FC=true : outs[v]    = relu(...) @ fc_w   fp32 [N]
template<bool FC>
__global__ __launch_bounds__(256) void gather_kernel(const unsigned* __restrict__ xwb,
                                                     const float* __restrict__ dinv,
                                                     const float* __restrict__ b,
                                                     const int* __restrict__ rowptr,
                                                     const int2* __restrict__ emeta,
                                                     const float* __restrict__ fcw,
                                                     unsigned* __restrict__ outb,
                                                     float* __restrict__ outs, int N) {
    int wid = threadIdx.x >> 6, lane = threadIdx.x & 63;
    int v = blockIdx.x * 4 + wid;
    if (v >= N) return;
    int e0 = rowptr[v], e1 = rowptr[v + 1];
    float d = dinv[v];
    float2 xs = unpack_bf16(xwb[(size_t)v * 64 + lane]);
    float2 bb = *(const float2*)(b + 2 * lane);
    float a0 = bb.x + d * d * xs.x;
    float a1 = bb.y + d * d * xs.y;

    int e = e0;
    for (; e + 4 <= e1; e += 4) {
        int2 m0 = emeta[e], m1 = emeta[e + 1], m2 = emeta[e + 2], m3 = emeta[e + 3];
        unsigned u0 = xwb[(size_t)m0.x * 64 + lane];
        unsigned u1 = xwb[(size_t)m1.x * 64 + lane];
        unsigned u2 = xwb[(size_t)m2.x * 64 + lane];
        unsigned u3 = xwb[(size_t)m3.x * 64 + lane];
        float w0 = __int_as_float(m0.y), w1 = __int_as_float(m1.y);
        float w2 = __int_as_float(m2.y), w3 = __int_as_float(m3.y);
        float2 f0 = unpack_bf16(u0), f1 = unpack_bf16(u1);
        float2 f2 = unpack_bf16(u2), f3 = unpack_bf16(u3);
        a0 = fmaf(w0, f0.x, a0); a1 = fmaf(w0, f0.y, a1);
        a0 = fmaf(w1, f1.x, a0); a1 = fmaf(w1, f1.y, a1);
        a0 = fmaf(w2, f2.x, a0); a1 = fmaf(w2, f2.y, a1);
        a0 = fmaf(w3, f3.x, a0); a1 = fmaf(w3, f3.y, a1);
    }
    for (; e < e1; ++e) {
        int2 m = emeta[e];
        float2 f = unpack_bf16(xwb[(size_t)m.x * 64 + lane]);
        float w = __int_as_float(m.y);
        a0 = fmaf(w, f.x, a0); a1 = fmaf(w, f.y, a1);
    }

    a0 = fmaxf(a0, 0.f); a1 = fmaxf(a1, 0.f);
    if (!FC) {
        outb[(size_t)v * 64 + lane] = pack_bf16(a0, a1);
    } else {
        float2 wv = *(const float2*)(fcw + 2 * lane);
        float s = a0 * wv.x + a1 * wv.y;
        #pragma unroll
        for (int m = 32; m > 0; m >>= 1) s += __shfl_xor(s, m, 64);
        if (lane == 0) outs[v] = s;
    }
}

// out[g] = (sum_{v in g} s[v]) / max(cnt,1) + fc_b    (one block per graph)
__global__ __launch_bounds__(256) void pool_kernel(const float* __restrict__ s,
                                                   const int* __restrict__ start,
                                                   const float* __restrict__ fc_b,
                                                   float* __restrict__ out) {
    int g = blockIdx.x;
    int s0 = start[g], s1 = start[g + 1];
    float acc = 0.f;
    for (int v = s0 + threadIdx.x; v < s1; v += 256) acc += s[v];
    __shared__ float red[256];
    red[threadIdx.x] = acc;
    __syncthreads();
    #pragma unroll
    for (int off = 128; off > 0; off >>= 1) {
        if (threadIdx.x < off) red[threadIdx.x] += red[threadIdx.x + off];
        __syncthreads();
    }
    if (threadIdx.x == 0) {
        float cnt = (float)(s1 - s0);
        out[g] = red[0] / fmaxf(cnt, 1.f) + fc_b[0];
    }
}

extern "C" void kernel_launch(void* const* d_in, const int* in_sizes, int n_in,
                              void* d_out, int out_size, void* d_ws, size_t ws_size,
                              hipStream_t stream) {
    const float* x     = (const float*)d_in[0];
    const int*   ei    = (const int*)d_in[1];
    const int*   batch = (const int*)d_in[2];
    const float* W1    = (const float*)d_in[3];
    const float* b1    = (const float*)d_in[4];
    const float* W2    = (const float*)d_in[5];
    const float* b2    = (const float*)d_in[6];
    const float* fcw   = (const float*)d_in[7];
    const float* fcb   = (const float*)d_in[8];
    float* out = (float*)d_out;

    const int N = in_sizes[2];
    const int E = in_sizes[1] / 2;
    const int G = out_size;
    const int* row = ei;       // edge_index[0]
    const int* col = ei + E;   // edge_index[1]

    auto align512 = [](size_t v) { return (v + 511) & ~(size_t)511; };
    char* ws = (char*)d_ws;
    size_t o = 0;
    int*      deg      = (int*)(ws + o);      o += align512((size_t)N * 4);
    float*    dinv     = (float*)(ws + o);    o += align512((size_t)N * 4);
    int*      rowptr   = (int*)(ws + o);      o += align512((size_t)(N + 1) * 4);
    int*      cursor   = (int*)(ws + o);      o += align512((size_t)N * 4);
    int*      blocksum = (int*)(ws + o);      o += align512(1024 * 4);
    int*      start    = (int*)(ws + o);      o += align512((size_t)(G + 1) * 4);
    float*    nodesc   = (float*)(ws + o);    o += align512((size_t)N * 4);
    unsigned* Wf1      = (unsigned*)(ws + o); o += align512(8192 * 4);
    unsigned* Wf2      = (unsigned*)(ws + o); o += align512(8192 * 4);
    int2*     emeta    = (int2*)(ws + o);     o += align512((size_t)E * 8);
    unsigned* bufBF    = (unsigned*)(ws + o); o += align512((size_t)N * 64 * 4);
    unsigned* bufBF2   = (unsigned*)(ws + o);

    const int nb = (N + 1023) / 1024;

    hipMemsetAsync(deg, 0, (size_t)N * 4, stream);
    deg_kernel<<<(E + 255) / 256, 256, 0, stream>>>(col, deg, E);
    dinv_kernel<<<(N + 255) / 256, 256, 0, stream>>>(deg, dinv, N);
    scan1<<<nb, 256, 0, stream>>>(deg, blocksum, N);
    scan2<<<1, 1024, 0, stream>>>(blocksum, nb);
    scan3<<<nb, 256, 0, stream>>>(deg, blocksum, rowptr, cursor, N, E);
    fill_kernel<<<(E + 255) / 256, 256, 0, stream>>>(row, col, dinv, cursor, emeta, E);
    bounds_kernel<<<1, 128, 0, stream>>>(batch, start, N, G);
    wprep_kernel<<<32, 256, 0, stream>>>(W1, Wf1);
    wprep_kernel<<<32, 256, 0, stream>>>(W2, Wf2);

    const int gemm_blocks = (N + 255) / 256;
    const int gather_blocks = (N + 3) / 4;

    // layer 1
    gemm_mfma<true><<<gemm_blocks, 256, 0, stream>>>(x, Wf1, bufBF, N);
    gather_kernel<false><<<gather_blocks, 256, 0, stream>>>(bufBF, dinv, b1, rowptr, emeta,
                                                            nullptr, bufBF2, nullptr, N);

    // layer 2: gather fuses relu + fc dot -> per-node scalar
    gemm_mfma<false><<<gemm_blocks, 256, 0, stream>>>(bufBF2, Wf2, bufBF, N);
    gather_kernel<true><<<gather_blocks, 256, 0, stream>>>(bufBF, dinv, b2, rowptr, emeta,
                                                           fcw, nullptr, nodesc, N);

    // segmented mean over per-node scalars
    pool_kernel<<<G, 256, 0, stream>>>(nodesc, start, fcb, out);
}